// Round 2
// baseline (2100.996 us; speedup 1.0000x reference)
//
#include <hip/hip_runtime.h>
#include <cstdint>
#include <cstddef>

// ---------------------------------------------------------------------------
// MixedHead: 2-layer dual-stream transformer forward on MI355X (gfx950).
// All GEMMs as bf16 MFMA (16x16x32), fp32 accumulate, fused epilogues.
// ---------------------------------------------------------------------------

#define NTOK   16384      // B*T
#define TWO_N  32768
#define DMODEL 512
#define HEADS  8
#define HDIM   64
#define FFDIM  1024
#define KSTOCH 1024
#define KDETER 4096
#define QKVD   1536
#define NOUT   255

typedef short bf16x8 __attribute__((ext_vector_type(8)));
typedef float f32x4  __attribute__((ext_vector_type(4)));

__device__ inline unsigned short bfbits(float f) {
  union { float f; unsigned u; } x; x.f = f;
  unsigned r = x.u + 0x7fffu + ((x.u >> 16) & 1u);   // RNE
  return (unsigned short)(r >> 16);
}
__device__ inline float bf2f(unsigned short s) {
  union { unsigned u; float f; } x; x.u = ((unsigned)s) << 16;
  return x.f;
}
__device__ inline float wave_sum(float v) {
  #pragma unroll
  for (int o = 32; o > 0; o >>= 1) v += __shfl_xor(v, o);
  return v;
}

// ---------------------------------------------------------------------------
// Batched f32 -> bf16 conversion (inputs + all weights). Wm is padded with a
// zero row to 256 so the 128-wide GEMM tile never reads OOB.
// ---------------------------------------------------------------------------
struct CvtEnt { const float* src; unsigned short* dst; int n4; int ntot4; };
struct CvtArgs { CvtEnt e[11]; };

__global__ __launch_bounds__(256) void cvt_kernel(CvtArgs args) {
  CvtEnt ent = args.e[blockIdx.y];
  int stride = gridDim.x * 256;
  for (int i = blockIdx.x * 256 + threadIdx.x; i < ent.ntot4; i += stride) {
    float4 v;
    if (i < ent.n4) v = ((const float4*)ent.src)[i];
    else            v = make_float4(0.f, 0.f, 0.f, 0.f);
    ushort4 o;
    o.x = bfbits(v.x); o.y = bfbits(v.y); o.z = bfbits(v.z); o.w = bfbits(v.w);
    ((ushort4*)ent.dst)[i] = o;
  }
}

// q2[n,:] = emb[tg[n],:]   (f32 row gather, 1 block per row, float4 copies)
__global__ __launch_bounds__(128) void gather_kernel(
    const float* __restrict__ emb, const int* __restrict__ tg,
    float* __restrict__ q2) {
  int n = blockIdx.x;
  int row = tg[n];
  ((float4*)(q2 + (size_t)n * DMODEL))[threadIdx.x] =
      ((const float4*)(emb + (size_t)row * DMODEL))[threadIdx.x];
}

// ---------------------------------------------------------------------------
// LayerNorm over D=512. One wave per row (lane holds 8 elems), writes f32+bf16.
// ---------------------------------------------------------------------------
__global__ __launch_bounds__(256) void ln_kernel(
    const float* __restrict__ x, const float* __restrict__ g,
    const float* __restrict__ b, float* __restrict__ of,
    unsigned short* __restrict__ ob, int rows) {
  int w = threadIdx.x >> 6, l = threadIdx.x & 63;
  long row = (long)blockIdx.x * 4 + w;
  if (row >= rows) return;
  const float* xr = x + row * DMODEL;
  float4 v0 = ((const float4*)xr)[l];
  float4 v1 = ((const float4*)xr)[l + 64];
  float s  = v0.x + v0.y + v0.z + v0.w + v1.x + v1.y + v1.z + v1.w;
  float ss = v0.x*v0.x + v0.y*v0.y + v0.z*v0.z + v0.w*v0.w
           + v1.x*v1.x + v1.y*v1.y + v1.z*v1.z + v1.w*v1.w;
  s = wave_sum(s); ss = wave_sum(ss);
  float mean = s * (1.f / DMODEL);
  float var  = ss * (1.f / DMODEL) - mean * mean;
  float r = rsqrtf(var + 1e-5f);

  float4 g0 = ((const float4*)g)[l],      b0 = ((const float4*)b)[l];
  float4 g1 = ((const float4*)g)[l + 64], b1 = ((const float4*)b)[l + 64];
  float4 o0, o1;
  o0.x = (v0.x - mean) * r * g0.x + b0.x;  o0.y = (v0.y - mean) * r * g0.y + b0.y;
  o0.z = (v0.z - mean) * r * g0.z + b0.z;  o0.w = (v0.w - mean) * r * g0.w + b0.w;
  o1.x = (v1.x - mean) * r * g1.x + b1.x;  o1.y = (v1.y - mean) * r * g1.y + b1.y;
  o1.z = (v1.z - mean) * r * g1.z + b1.z;  o1.w = (v1.w - mean) * r * g1.w + b1.w;
  float* ofr = of + row * DMODEL;
  ((float4*)ofr)[l] = o0; ((float4*)ofr)[l + 64] = o1;
  unsigned short* obr = ob + row * DMODEL;
  ushort4 p0, p1;
  p0.x = bfbits(o0.x); p0.y = bfbits(o0.y); p0.z = bfbits(o0.z); p0.w = bfbits(o0.w);
  p1.x = bfbits(o1.x); p1.y = bfbits(o1.y); p1.z = bfbits(o1.z); p1.w = bfbits(o1.w);
  ((ushort4*)obr)[l] = p0; ((ushort4*)obr)[l + 64] = p1;
}

// ---------------------------------------------------------------------------
// Attention: seq-len-2 log-softmax attention + cross-stream query.
// One wave per (token, head); lane = d in [0,64).
// ---------------------------------------------------------------------------
__global__ __launch_bounds__(256) void attn_kernel(
    const unsigned short* __restrict__ qkv, const unsigned short* __restrict__ qnb,
    const float* __restrict__ qnf, float* __restrict__ q2,
    unsigned short* __restrict__ attnout) {
  int w = threadIdx.x >> 6, l = threadIdx.x & 63;
  int idx = blockIdx.x * 4 + w;          // n*HEADS + h
  int n = idx >> 3, h = idx & 7;
  const unsigned short* r0 = qkv + (size_t)(2 * n) * QKVD + h * HDIM + l;
  float q0 = bf2f(r0[0]),     k0 = bf2f(r0[512]),      v0 = bf2f(r0[1024]);
  float q1 = bf2f(r0[QKVD]),  k1 = bf2f(r0[QKVD+512]), v1 = bf2f(r0[QKVD+1024]);
  size_t qoff = (size_t)n * DMODEL + h * HDIM + l;
  float qq = bf2f(qnb[qoff]);

  float d00 = q0*k0, d01 = q0*k1, d10 = q1*k0, d11 = q1*k1, e0 = qq*k0, e1 = qq*k1;
  #pragma unroll
  for (int o = 32; o > 0; o >>= 1) {
    d00 += __shfl_xor(d00, o); d01 += __shfl_xor(d01, o);
    d10 += __shfl_xor(d10, o); d11 += __shfl_xor(d11, o);
    e0  += __shfl_xor(e0, o);  e1  += __shfl_xor(e1, o);
  }
  const float SC = 0.125f;   // 64^-0.5
  d00 *= SC; d01 *= SC; d10 *= SC; d11 *= SC; e0 *= SC; e1 *= SC;
  // log_softmax over 2 entries
  auto lsm2 = [](float& a, float& b) {
    float m = fmaxf(a, b);
    float lse = m + logf(expf(a - m) + expf(b - m));
    a -= lse; b -= lse;
  };
  lsm2(d00, d01); lsm2(d10, d11); lsm2(e0, e1);

  float o0 = d00 * v0 + d01 * v1;
  float o1 = d10 * v0 + d11 * v1;
  float oq = e0 * v0 + e1 * v1;
  attnout[(size_t)(2 * n)     * DMODEL + h * HDIM + l] = bfbits(o0);
  attnout[(size_t)(2 * n + 1) * DMODEL + h * HDIM + l] = bfbits(o1);
  q2[qoff] = oq + qnf[qoff];
}

// ---------------------------------------------------------------------------
// bf16 MFMA GEMM: C[M,N] = A[M,K] * B[N,K]^T  (+bias, +GELU, +res)
// 128x128 tile, 4 waves (2x2), 4x4 16x16x32 frags each, BK=64,
// global_load_lds width-16 staging (4 issues/wave/operand = full 128x64 tile),
// 2-barrier K loop (m97 structure).
// ---------------------------------------------------------------------------
template <bool GELU>
__global__ __launch_bounds__(256, 2) void gemm_kernel(
    const unsigned short* __restrict__ A, const unsigned short* __restrict__ B,
    const float* __restrict__ bias, const float* __restrict__ res,
    float* __restrict__ Cf, unsigned short* __restrict__ Cb,
    int M, int Nvalid, int K, int ldc, int ldcb, int ldres, int ntn) {
  __shared__ short lsA[128 * 64];
  __shared__ short lsB[128 * 64];
  int tm = blockIdx.x / ntn, tn = blockIdx.x % ntn;
  int tid = threadIdx.x;
  int w = tid >> 6, l = tid & 63;
  int wr = w >> 1, wc = w & 1;

  // staging: wave w covers rows [w*32, w*32+32) of each 128x64 tile.
  // One global_load_lds stages 8 rows (64 lanes x 16B); 4 issues per operand.
  // lane l -> row base + l/8, bf16 col (l%8)*8; LDS linear row-major [128][64].
  int srow = w * 32 + (l >> 3);
  int scol = (l & 7) * 8;
  const unsigned short* ga = A + (size_t)(tm * 128 + srow) * K + scol;
  const unsigned short* gb = B + (size_t)(tn * 128 + srow) * K + scol;
  short* la = lsA + w * 2048;   // wave-uniform LDS base (HW adds lane*16B)
  short* lb = lsB + w * 2048;

  f32x4 acc[4][4] = {};

  for (int k0 = 0; k0 < K; k0 += 64) {
    #pragma unroll
    for (int r = 0; r < 4; ++r) {
      __builtin_amdgcn_global_load_lds(
          (const __attribute__((address_space(1))) void*)(ga + k0 + (size_t)r * 8 * K),
          (__attribute__((address_space(3))) void*)(la + r * 512), 16, 0, 0);
      __builtin_amdgcn_global_load_lds(
          (const __attribute__((address_space(1))) void*)(gb + k0 + (size_t)r * 8 * K),
          (__attribute__((address_space(3))) void*)(lb + r * 512), 16, 0, 0);
    }
    __syncthreads();
    #pragma unroll
    for (int kk = 0; kk < 2; ++kk) {
      bf16x8 af[4], bfr[4];
      #pragma unroll
      for (int i = 0; i < 4; ++i)
        af[i] = *(const bf16x8*)(lsA + (wr * 64 + i * 16 + (l & 15)) * 64 +
                                 kk * 32 + (l >> 4) * 8);
      #pragma unroll
      for (int i = 0; i < 4; ++i)
        bfr[i] = *(const bf16x8*)(lsB + (wc * 64 + i * 16 + (l & 15)) * 64 +
                                  kk * 32 + (l >> 4) * 8);
      #pragma unroll
      for (int mi = 0; mi < 4; ++mi)
        #pragma unroll
        for (int ni = 0; ni < 4; ++ni)
          acc[mi][ni] = __builtin_amdgcn_mfma_f32_16x16x32_bf16(
              af[mi], bfr[ni], acc[mi][ni], 0, 0, 0);
    }
    __syncthreads();
  }

  // epilogue: C/D layout col = lane&15, row = (lane>>4)*4 + reg
  int lr = l >> 4, lc = l & 15;
  #pragma unroll
  for (int mi = 0; mi < 4; ++mi) {
    #pragma unroll
    for (int ni = 0; ni < 4; ++ni) {
      int gn = tn * 128 + wc * 64 + ni * 16 + lc;
      bool okn = gn < Nvalid;
      float bv = (bias != nullptr && okn) ? bias[gn] : 0.f;
      f32x4 a = acc[mi][ni];
      #pragma unroll
      for (int j = 0; j < 4; ++j) {
        int gm = tm * 128 + wr * 64 + mi * 16 + lr * 4 + j;
        float v = a[j] + bv;
        if (GELU) v = 0.5f * v * (1.f + erff(v * 0.70710678118654752f));
        if (okn) {
          if (res) v += res[(size_t)gm * ldres + gn];
          if (Cf) Cf[(size_t)gm * ldc + gn] = v;
          if (Cb) Cb[(size_t)gm * ldcb + gn] = bfbits(v);
        }
      }
    }
  }
}

// ---------------------------------------------------------------------------
extern "C" void kernel_launch(void* const* d_in, const int* in_sizes, int n_in,
                              void* d_out, int out_size, void* d_ws, size_t ws_size,
                              hipStream_t stream) {
  const float* stoch = (const float*)d_in[0];
  const float* deter = (const float*)d_in[1];
  const int*   tg    = (const int*)d_in[2];
  const float* emb   = (const float*)d_in[3];
  const float* Ws    = (const float*)d_in[4];
  const float* bs    = (const float*)d_in[5];
  const float* Wd    = (const float*)d_in[6];
  const float* bd    = (const float*)d_in[7];
  const float* ln1g  = (const float*)d_in[8];
  const float* ln1b  = (const float*)d_in[9];
  const float* Wqkv  = (const float*)d_in[10];
  const float* Wout  = (const float*)d_in[11];
  const float* bout  = (const float*)d_in[12];
  const float* ln2g  = (const float*)d_in[13];
  const float* ln2b  = (const float*)d_in[14];
  const float* W1    = (const float*)d_in[15];
  const float* b1    = (const float*)d_in[16];
  const float* W2    = (const float*)d_in[17];
  const float* b2    = (const float*)d_in[18];
  const float* W1b   = (const float*)d_in[19];
  const float* b1b   = (const float*)d_in[20];
  const float* W2b   = (const float*)d_in[21];
  const float* b2b   = (const float*)d_in[22];
  const float* Wm    = (const float*)d_in[23];
  const float* bm    = (const float*)d_in[24];
  float* out = (float*)d_out;

  // workspace carve-up (all sizes are multiples of 256B)
  char* p = (char*)d_ws;
  size_t off = 0;
  auto alloc = [&](size_t bytes) {
    void* r = p + off;
    off += (bytes + 255) & ~(size_t)255;
    return r;
  };
  unsigned short* s_bf = (unsigned short*)alloc((size_t)NTOK * KSTOCH * 2);
  unsigned short* d_bf = (unsigned short*)alloc((size_t)NTOK * KDETER * 2);
  float* x    = (float*)alloc((size_t)TWO_N * DMODEL * 4);
  float* q2   = (float*)alloc((size_t)NTOK * DMODEL * 4);
  float* xnf  = (float*)alloc((size_t)TWO_N * DMODEL * 4);
  float* qnf  = (float*)alloc((size_t)NTOK * DMODEL * 4);
  unsigned short* xnb  = (unsigned short*)alloc((size_t)TWO_N * DMODEL * 2);
  unsigned short* qnb  = (unsigned short*)alloc((size_t)NTOK * DMODEL * 2);
  unsigned short* qkvb = (unsigned short*)alloc((size_t)TWO_N * QKVD * 2);
  unsigned short* Wsb   = (unsigned short*)alloc((size_t)DMODEL * KSTOCH * 2);
  unsigned short* Wdb   = (unsigned short*)alloc((size_t)DMODEL * KDETER * 2);
  unsigned short* Wqkvb = (unsigned short*)alloc((size_t)2 * QKVD * DMODEL * 2);
  unsigned short* Woutb = (unsigned short*)alloc((size_t)2 * DMODEL * DMODEL * 2);
  unsigned short* W1bf  = (unsigned short*)alloc((size_t)2 * FFDIM * DMODEL * 2);
  unsigned short* W2bf  = (unsigned short*)alloc((size_t)2 * DMODEL * FFDIM * 2);
  unsigned short* W1bbf = (unsigned short*)alloc((size_t)2 * FFDIM * DMODEL * 2);
  unsigned short* W2bbf = (unsigned short*)alloc((size_t)2 * DMODEL * FFDIM * 2);
  unsigned short* Wmb   = (unsigned short*)alloc((size_t)256 * DMODEL * 2);
  // aliases over dead regions:
  unsigned short* attnout = s_bf;                       // dead after tok1 GEMM
  unsigned short* q2b     = d_bf;                       // dead after tok2 GEMM
  unsigned short* hb      = qkvb;                       // dead after attention
  unsigned short* hqb     = qkvb + (size_t)TWO_N * FFDIM;

  // 1) convert inputs + weights to bf16 (one batched kernel)
  CvtArgs ca;
  ca.e[0]  = { stoch, s_bf,  NTOK * KSTOCH / 4,  NTOK * KSTOCH / 4 };
  ca.e[1]  = { deter, d_bf,  NTOK * KDETER / 4,  NTOK * KDETER / 4 };
  ca.e[2]  = { Ws,    Wsb,   DMODEL * KSTOCH / 4, DMODEL * KSTOCH / 4 };
  ca.e[3]  = { Wd,    Wdb,   DMODEL * KDETER / 4, DMODEL * KDETER / 4 };
  ca.e[4]  = { Wqkv,  Wqkvb, 2 * QKVD * DMODEL / 4, 2 * QKVD * DMODEL / 4 };
  ca.e[5]  = { Wout,  Woutb, 2 * DMODEL * DMODEL / 4, 2 * DMODEL * DMODEL / 4 };
  ca.e[6]  = { W1,    W1bf,  2 * FFDIM * DMODEL / 4, 2 * FFDIM * DMODEL / 4 };
  ca.e[7]  = { W2,    W2bf,  2 * DMODEL * FFDIM / 4, 2 * DMODEL * FFDIM / 4 };
  ca.e[8]  = { W1b,   W1bbf, 2 * FFDIM * DMODEL / 4, 2 * FFDIM * DMODEL / 4 };
  ca.e[9]  = { W2b,   W2bbf, 2 * DMODEL * FFDIM / 4, 2 * DMODEL * FFDIM / 4 };
  ca.e[10] = { Wm,    Wmb,   NOUT * DMODEL / 4,   256 * DMODEL / 4 };  // pad row 255 with 0
  cvt_kernel<<<dim3(1024, 11), 256, 0, stream>>>(ca);

  // 2) token projections into interleaved x[N,2,D] (row stride trick ldc=1024)
  gemm_kernel<false><<<128 * 4, 256, 0, stream>>>(
      s_bf, Wsb, bs, nullptr, x, nullptr, NTOK, DMODEL, KSTOCH, 2 * DMODEL, 0, 0, 4);
  gemm_kernel<false><<<128 * 4, 256, 0, stream>>>(
      d_bf, Wdb, bd, nullptr, x + DMODEL, nullptr, NTOK, DMODEL, KDETER, 2 * DMODEL, 0, 0, 4);

  // 3) q2 = emb[targets]
  gather_kernel<<<NTOK, 128, 0, stream>>>(emb, tg, q2);

  for (int l = 0; l < 2; ++l) {
    // PreNorm (ln1)
    ln_kernel<<<TWO_N / 4, 256, 0, stream>>>(x, ln1g + 512 * l, ln1b + 512 * l, xnf, xnb, TWO_N);
    ln_kernel<<<NTOK / 4, 256, 0, stream>>>(q2, ln1g + 512 * l, ln1b + 512 * l, qnf, qnb, NTOK);
    // qkv projection (no bias), bf16 out
    gemm_kernel<false><<<256 * 12, 256, 0, stream>>>(
        xnb, Wqkvb + (size_t)l * QKVD * DMODEL, nullptr, nullptr, nullptr, qkvb,
        TWO_N, QKVD, DMODEL, 0, QKVD, 0, 12);
    // attention (updates q2 in place with qout + qn)
    attn_kernel<<<NTOK * HEADS / 4, 256, 0, stream>>>(qkvb, qnb, qnf, q2, attnout);
    // out projection + bout + xn residual -> x
    gemm_kernel<false><<<256 * 4, 256, 0, stream>>>(
        attnout, Woutb + (size_t)l * DMODEL * DMODEL, bout + 512 * l, xnf, x, nullptr,
        TWO_N, DMODEL, DMODEL, DMODEL, 0, DMODEL, 4);
    // PreNorm (ln2)
    ln_kernel<<<TWO_N / 4, 256, 0, stream>>>(x, ln2g + 512 * l, ln2b + 512 * l, xnf, xnb, TWO_N);
    ln_kernel<<<NTOK / 4, 256, 0, stream>>>(q2, ln2g + 512 * l, ln2b + 512 * l, qnf, qnb, NTOK);
    // FF x-stream
    gemm_kernel<true><<<256 * 8, 256, 0, stream>>>(
        xnb, W1bf + (size_t)l * FFDIM * DMODEL, b1 + 1024 * l, nullptr, nullptr, hb,
        TWO_N, FFDIM, DMODEL, 0, FFDIM, 0, 8);
    gemm_kernel<false><<<256 * 4, 256, 0, stream>>>(
        hb, W2bf + (size_t)l * DMODEL * FFDIM, b2 + 512 * l, xnf, x, nullptr,
        TWO_N, DMODEL, FFDIM, DMODEL, 0, DMODEL, 4);
    // FF q-stream (also keeps a bf16 copy of q2 for the head GEMM)
    gemm_kernel<true><<<128 * 8, 256, 0, stream>>>(
        qnb, W1bbf + (size_t)l * FFDIM * DMODEL, b1b + 1024 * l, nullptr, nullptr, hqb,
        NTOK, FFDIM, DMODEL, 0, FFDIM, 0, 8);
    gemm_kernel<false><<<128 * 4, 256, 0, stream>>>(
        hqb, W2bbf + (size_t)l * DMODEL * FFDIM, b2b + 512 * l, qnf, q2, q2b,
        NTOK, DMODEL, FFDIM, DMODEL, DMODEL, DMODEL, 4);
  }

  // head: mean = q2 @ Wm.T + bm  -> d_out [N,255] f32
  gemm_kernel<false><<<128 * 2, 256, 0, stream>>>(
      q2b, Wmb, bm, nullptr, out, nullptr, NTOK, NOUT, DMODEL, NOUT, 0, 0, 2);

  (void)in_sizes; (void)n_in; (void)out_size; (void)ws_size;
}

// Round 3
// 1809.555 us; speedup vs baseline: 1.1611x; 1.1611x over previous
//
#include <hip/hip_runtime.h>
#include <cstdint>
#include <cstddef>

// ---------------------------------------------------------------------------
// MixedHead: 2-layer dual-stream transformer forward on MI355X (gfx950).
// All GEMMs as bf16 MFMA (16x16x32), fp32 accumulate, fused epilogues.
// R3: XCD-aware block swizzle (T1), bf16 residuals (no f32 xn/qn buffers),
//     launch_bounds(256,3), merged LN dispatches.
// ---------------------------------------------------------------------------

#define NTOK   16384      // B*T
#define TWO_N  32768
#define DMODEL 512
#define HEADS  8
#define HDIM   64
#define FFDIM  1024
#define KSTOCH 1024
#define KDETER 4096
#define QKVD   1536
#define NOUT   255

typedef short bf16x8 __attribute__((ext_vector_type(8)));
typedef float f32x4  __attribute__((ext_vector_type(4)));

__device__ inline unsigned short bfbits(float f) {
  union { float f; unsigned u; } x; x.f = f;
  unsigned r = x.u + 0x7fffu + ((x.u >> 16) & 1u);   // RNE
  return (unsigned short)(r >> 16);
}
__device__ inline float bf2f(unsigned short s) {
  union { unsigned u; float f; } x; x.u = ((unsigned)s) << 16;
  return x.f;
}
__device__ inline float wave_sum(float v) {
  #pragma unroll
  for (int o = 32; o > 0; o >>= 1) v += __shfl_xor(v, o);
  return v;
}

// ---------------------------------------------------------------------------
// Batched f32 -> bf16 conversion (inputs + all weights). Wm is padded with a
// zero row to 256 so the 128-wide GEMM tile never reads OOB.
// ---------------------------------------------------------------------------
struct CvtEnt { const float* src; unsigned short* dst; int n4; int ntot4; };
struct CvtArgs { CvtEnt e[11]; };

__global__ __launch_bounds__(256) void cvt_kernel(CvtArgs args) {
  CvtEnt ent = args.e[blockIdx.y];
  int stride = gridDim.x * 256;
  for (int i = blockIdx.x * 256 + threadIdx.x; i < ent.ntot4; i += stride) {
    float4 v;
    if (i < ent.n4) v = ((const float4*)ent.src)[i];
    else            v = make_float4(0.f, 0.f, 0.f, 0.f);
    ushort4 o;
    o.x = bfbits(v.x); o.y = bfbits(v.y); o.z = bfbits(v.z); o.w = bfbits(v.w);
    ((ushort4*)ent.dst)[i] = o;
  }
}

// q2[n,:] = emb[tg[n],:]   (f32 row gather, 1 block per row, float4 copies)
__global__ __launch_bounds__(128) void gather_kernel(
    const float* __restrict__ emb, const int* __restrict__ tg,
    float* __restrict__ q2) {
  int n = blockIdx.x;
  int row = tg[n];
  ((float4*)(q2 + (size_t)n * DMODEL))[threadIdx.x] =
      ((const float4*)(emb + (size_t)row * DMODEL))[threadIdx.x];
}

// ---------------------------------------------------------------------------
// LayerNorm over D=512 for BOTH streams in one dispatch. One wave per row,
// writes bf16 only (residuals consume bf16 now).
// rows [0, TWO_N) -> x stream; rows [TWO_N, TWO_N+NTOK) -> q stream.
// ---------------------------------------------------------------------------
__global__ __launch_bounds__(256) void ln2_kernel(
    const float* __restrict__ xs, const float* __restrict__ qs,
    const float* __restrict__ g, const float* __restrict__ b,
    unsigned short* __restrict__ xb, unsigned short* __restrict__ qb) {
  int w = threadIdx.x >> 6, l = threadIdx.x & 63;
  int row = blockIdx.x * 4 + w;
  const float* src;
  unsigned short* dst;
  if (row < TWO_N) {
    src = xs + (size_t)row * DMODEL;
    dst = xb + (size_t)row * DMODEL;
  } else {
    int r2 = row - TWO_N;
    src = qs + (size_t)r2 * DMODEL;
    dst = qb + (size_t)r2 * DMODEL;
  }
  float4 v0 = ((const float4*)src)[l];
  float4 v1 = ((const float4*)src)[l + 64];
  float s  = v0.x + v0.y + v0.z + v0.w + v1.x + v1.y + v1.z + v1.w;
  float ss = v0.x*v0.x + v0.y*v0.y + v0.z*v0.z + v0.w*v0.w
           + v1.x*v1.x + v1.y*v1.y + v1.z*v1.z + v1.w*v1.w;
  s = wave_sum(s); ss = wave_sum(ss);
  float mean = s * (1.f / DMODEL);
  float var  = ss * (1.f / DMODEL) - mean * mean;
  float r = rsqrtf(var + 1e-5f);

  float4 g0 = ((const float4*)g)[l],      b0 = ((const float4*)b)[l];
  float4 g1 = ((const float4*)g)[l + 64], b1 = ((const float4*)b)[l + 64];
  ushort4 p0, p1;
  p0.x = bfbits((v0.x - mean) * r * g0.x + b0.x);
  p0.y = bfbits((v0.y - mean) * r * g0.y + b0.y);
  p0.z = bfbits((v0.z - mean) * r * g0.z + b0.z);
  p0.w = bfbits((v0.w - mean) * r * g0.w + b0.w);
  p1.x = bfbits((v1.x - mean) * r * g1.x + b1.x);
  p1.y = bfbits((v1.y - mean) * r * g1.y + b1.y);
  p1.z = bfbits((v1.z - mean) * r * g1.z + b1.z);
  p1.w = bfbits((v1.w - mean) * r * g1.w + b1.w);
  ((ushort4*)dst)[l] = p0; ((ushort4*)dst)[l + 64] = p1;
}

// ---------------------------------------------------------------------------
// Attention: seq-len-2 log-softmax attention + cross-stream query.
// One wave per (token, head); lane = d in [0,64).
// q2 residual uses qq (= qn at this offset), already loaded as bf16.
// ---------------------------------------------------------------------------
__global__ __launch_bounds__(256) void attn_kernel(
    const unsigned short* __restrict__ qkv, const unsigned short* __restrict__ qnb,
    float* __restrict__ q2, unsigned short* __restrict__ attnout) {
  int w = threadIdx.x >> 6, l = threadIdx.x & 63;
  int idx = blockIdx.x * 4 + w;          // n*HEADS + h
  int n = idx >> 3, h = idx & 7;
  const unsigned short* r0 = qkv + (size_t)(2 * n) * QKVD + h * HDIM + l;
  float q0 = bf2f(r0[0]),     k0 = bf2f(r0[512]),      v0 = bf2f(r0[1024]);
  float q1 = bf2f(r0[QKVD]),  k1 = bf2f(r0[QKVD+512]), v1 = bf2f(r0[QKVD+1024]);
  size_t qoff = (size_t)n * DMODEL + h * HDIM + l;
  float qq = bf2f(qnb[qoff]);

  float d00 = q0*k0, d01 = q0*k1, d10 = q1*k0, d11 = q1*k1, e0 = qq*k0, e1 = qq*k1;
  #pragma unroll
  for (int o = 32; o > 0; o >>= 1) {
    d00 += __shfl_xor(d00, o); d01 += __shfl_xor(d01, o);
    d10 += __shfl_xor(d10, o); d11 += __shfl_xor(d11, o);
    e0  += __shfl_xor(e0, o);  e1  += __shfl_xor(e1, o);
  }
  const float SC = 0.125f;   // 64^-0.5
  d00 *= SC; d01 *= SC; d10 *= SC; d11 *= SC; e0 *= SC; e1 *= SC;
  // log_softmax over 2 entries
  auto lsm2 = [](float& a, float& b) {
    float m = fmaxf(a, b);
    float lse = m + logf(expf(a - m) + expf(b - m));
    a -= lse; b -= lse;
  };
  lsm2(d00, d01); lsm2(d10, d11); lsm2(e0, e1);

  float o0 = d00 * v0 + d01 * v1;
  float o1 = d10 * v0 + d11 * v1;
  float oq = e0 * v0 + e1 * v1;
  attnout[(size_t)(2 * n)     * DMODEL + h * HDIM + l] = bfbits(o0);
  attnout[(size_t)(2 * n + 1) * DMODEL + h * HDIM + l] = bfbits(o1);
  q2[qoff] = oq + qq;
}

// ---------------------------------------------------------------------------
// bf16 MFMA GEMM: C[M,N] = A[M,K] * B[N,K]^T  (+bias, +GELU, +bf16 res)
// 128x128 tile, 4 waves (2x2), 4x4 16x16x32 frags each, BK=64,
// global_load_lds width-16 staging (4 issues/wave/operand = full 128x64 tile),
// 2-barrier K loop (m97 structure). T1 XCD-aware bijective block swizzle.
// ---------------------------------------------------------------------------
template <bool GELU>
__global__ __launch_bounds__(256, 3) void gemm_kernel(
    const unsigned short* __restrict__ A, const unsigned short* __restrict__ B,
    const float* __restrict__ bias, const unsigned short* __restrict__ res,
    float* __restrict__ Cf, unsigned short* __restrict__ Cb,
    int M, int Nvalid, int K, int ldc, int ldcb, int ldres, int ntn) {
  __shared__ short lsA[128 * 64];
  __shared__ short lsB[128 * 64];
  // T1: bijective chunked XCD swizzle — XCD k owns a contiguous logical range,
  // so the ntn blocks sharing an A panel land on the same XCD's L2.
  int nwg = gridDim.x;
  int q8 = nwg >> 3, r8 = nwg & 7;
  int xcd = blockIdx.x & 7, lin = blockIdx.x >> 3;
  int bid = (xcd < r8 ? xcd * (q8 + 1) : r8 * (q8 + 1) + (xcd - r8) * q8) + lin;
  int tm = bid / ntn, tn = bid % ntn;
  int tid = threadIdx.x;
  int w = tid >> 6, l = tid & 63;
  int wr = w >> 1, wc = w & 1;

  // staging: wave w covers rows [w*32, w*32+32) of each 128x64 tile.
  // One global_load_lds stages 8 rows (64 lanes x 16B); 4 issues per operand.
  // lane l -> row base + l/8, bf16 col (l%8)*8; LDS linear row-major [128][64].
  int srow = w * 32 + (l >> 3);
  int scol = (l & 7) * 8;
  const unsigned short* ga = A + (size_t)(tm * 128 + srow) * K + scol;
  const unsigned short* gb = B + (size_t)(tn * 128 + srow) * K + scol;
  short* la = lsA + w * 2048;   // wave-uniform LDS base (HW adds lane*16B)
  short* lb = lsB + w * 2048;

  f32x4 acc[4][4] = {};

  for (int k0 = 0; k0 < K; k0 += 64) {
    #pragma unroll
    for (int r = 0; r < 4; ++r) {
      __builtin_amdgcn_global_load_lds(
          (const __attribute__((address_space(1))) void*)(ga + k0 + (size_t)r * 8 * K),
          (__attribute__((address_space(3))) void*)(la + r * 512), 16, 0, 0);
      __builtin_amdgcn_global_load_lds(
          (const __attribute__((address_space(1))) void*)(gb + k0 + (size_t)r * 8 * K),
          (__attribute__((address_space(3))) void*)(lb + r * 512), 16, 0, 0);
    }
    __syncthreads();
    #pragma unroll
    for (int kk = 0; kk < 2; ++kk) {
      bf16x8 af[4], bfr[4];
      #pragma unroll
      for (int i = 0; i < 4; ++i)
        af[i] = *(const bf16x8*)(lsA + (wr * 64 + i * 16 + (l & 15)) * 64 +
                                 kk * 32 + (l >> 4) * 8);
      #pragma unroll
      for (int i = 0; i < 4; ++i)
        bfr[i] = *(const bf16x8*)(lsB + (wc * 64 + i * 16 + (l & 15)) * 64 +
                                  kk * 32 + (l >> 4) * 8);
      #pragma unroll
      for (int mi = 0; mi < 4; ++mi)
        #pragma unroll
        for (int ni = 0; ni < 4; ++ni)
          acc[mi][ni] = __builtin_amdgcn_mfma_f32_16x16x32_bf16(
              af[mi], bfr[ni], acc[mi][ni], 0, 0, 0);
    }
    __syncthreads();
  }

  // epilogue: C/D layout col = lane&15, row = (lane>>4)*4 + reg
  int lr = l >> 4, lc = l & 15;
  #pragma unroll
  for (int mi = 0; mi < 4; ++mi) {
    #pragma unroll
    for (int ni = 0; ni < 4; ++ni) {
      int gn = tn * 128 + wc * 64 + ni * 16 + lc;
      bool okn = gn < Nvalid;
      float bv = (bias != nullptr && okn) ? bias[gn] : 0.f;
      f32x4 a = acc[mi][ni];
      #pragma unroll
      for (int j = 0; j < 4; ++j) {
        int gm = tm * 128 + wr * 64 + mi * 16 + lr * 4 + j;
        float v = a[j] + bv;
        if (GELU) v = 0.5f * v * (1.f + erff(v * 0.70710678118654752f));
        if (okn) {
          if (res) v += bf2f(res[(size_t)gm * ldres + gn]);
          if (Cf) Cf[(size_t)gm * ldc + gn] = v;
          if (Cb) Cb[(size_t)gm * ldcb + gn] = bfbits(v);
        }
      }
    }
  }
}

// ---------------------------------------------------------------------------
extern "C" void kernel_launch(void* const* d_in, const int* in_sizes, int n_in,
                              void* d_out, int out_size, void* d_ws, size_t ws_size,
                              hipStream_t stream) {
  const float* stoch = (const float*)d_in[0];
  const float* deter = (const float*)d_in[1];
  const int*   tg    = (const int*)d_in[2];
  const float* emb   = (const float*)d_in[3];
  const float* Ws    = (const float*)d_in[4];
  const float* bs    = (const float*)d_in[5];
  const float* Wd    = (const float*)d_in[6];
  const float* bd    = (const float*)d_in[7];
  const float* ln1g  = (const float*)d_in[8];
  const float* ln1b  = (const float*)d_in[9];
  const float* Wqkv  = (const float*)d_in[10];
  const float* Wout  = (const float*)d_in[11];
  const float* bout  = (const float*)d_in[12];
  const float* ln2g  = (const float*)d_in[13];
  const float* ln2b  = (const float*)d_in[14];
  const float* W1    = (const float*)d_in[15];
  const float* b1    = (const float*)d_in[16];
  const float* W2    = (const float*)d_in[17];
  const float* b2    = (const float*)d_in[18];
  const float* W1b   = (const float*)d_in[19];
  const float* b1b   = (const float*)d_in[20];
  const float* W2b   = (const float*)d_in[21];
  const float* b2b   = (const float*)d_in[22];
  const float* Wm    = (const float*)d_in[23];
  const float* bm    = (const float*)d_in[24];
  float* out = (float*)d_out;

  // workspace carve-up (all sizes are multiples of 256B)
  char* p = (char*)d_ws;
  size_t off = 0;
  auto alloc = [&](size_t bytes) {
    void* r = p + off;
    off += (bytes + 255) & ~(size_t)255;
    return r;
  };
  unsigned short* s_bf = (unsigned short*)alloc((size_t)NTOK * KSTOCH * 2);
  unsigned short* d_bf = (unsigned short*)alloc((size_t)NTOK * KDETER * 2);
  float* x    = (float*)alloc((size_t)TWO_N * DMODEL * 4);
  float* q2   = (float*)alloc((size_t)NTOK * DMODEL * 4);
  unsigned short* xnb  = (unsigned short*)alloc((size_t)TWO_N * DMODEL * 2);
  unsigned short* qnb  = (unsigned short*)alloc((size_t)NTOK * DMODEL * 2);
  unsigned short* qkvb = (unsigned short*)alloc((size_t)TWO_N * QKVD * 2);
  unsigned short* Wsb   = (unsigned short*)alloc((size_t)DMODEL * KSTOCH * 2);
  unsigned short* Wdb   = (unsigned short*)alloc((size_t)DMODEL * KDETER * 2);
  unsigned short* Wqkvb = (unsigned short*)alloc((size_t)2 * QKVD * DMODEL * 2);
  unsigned short* Woutb = (unsigned short*)alloc((size_t)2 * DMODEL * DMODEL * 2);
  unsigned short* W1bf  = (unsigned short*)alloc((size_t)2 * FFDIM * DMODEL * 2);
  unsigned short* W2bf  = (unsigned short*)alloc((size_t)2 * DMODEL * FFDIM * 2);
  unsigned short* W1bbf = (unsigned short*)alloc((size_t)2 * FFDIM * DMODEL * 2);
  unsigned short* W2bbf = (unsigned short*)alloc((size_t)2 * DMODEL * FFDIM * 2);
  unsigned short* Wmb   = (unsigned short*)alloc((size_t)256 * DMODEL * 2);
  // aliases over dead regions:
  unsigned short* attnout = s_bf;                       // dead after tok1 GEMM
  unsigned short* q2b     = d_bf;                       // dead after tok2 GEMM
  unsigned short* hb      = qkvb;                       // dead after attention
  unsigned short* hqb     = qkvb + (size_t)TWO_N * FFDIM;

  // 1) convert inputs + weights to bf16 (one batched kernel)
  CvtArgs ca;
  ca.e[0]  = { stoch, s_bf,  NTOK * KSTOCH / 4,  NTOK * KSTOCH / 4 };
  ca.e[1]  = { deter, d_bf,  NTOK * KDETER / 4,  NTOK * KDETER / 4 };
  ca.e[2]  = { Ws,    Wsb,   DMODEL * KSTOCH / 4, DMODEL * KSTOCH / 4 };
  ca.e[3]  = { Wd,    Wdb,   DMODEL * KDETER / 4, DMODEL * KDETER / 4 };
  ca.e[4]  = { Wqkv,  Wqkvb, 2 * QKVD * DMODEL / 4, 2 * QKVD * DMODEL / 4 };
  ca.e[5]  = { Wout,  Woutb, 2 * DMODEL * DMODEL / 4, 2 * DMODEL * DMODEL / 4 };
  ca.e[6]  = { W1,    W1bf,  2 * FFDIM * DMODEL / 4, 2 * FFDIM * DMODEL / 4 };
  ca.e[7]  = { W2,    W2bf,  2 * DMODEL * FFDIM / 4, 2 * DMODEL * FFDIM / 4 };
  ca.e[8]  = { W1b,   W1bbf, 2 * FFDIM * DMODEL / 4, 2 * FFDIM * DMODEL / 4 };
  ca.e[9]  = { W2b,   W2bbf, 2 * DMODEL * FFDIM / 4, 2 * DMODEL * FFDIM / 4 };
  ca.e[10] = { Wm,    Wmb,   NOUT * DMODEL / 4,   256 * DMODEL / 4 };  // pad row 255 with 0
  cvt_kernel<<<dim3(1024, 11), 256, 0, stream>>>(ca);

  // 2) token projections into interleaved x[N,2,D] (row stride trick ldc=1024)
  gemm_kernel<false><<<128 * 4, 256, 0, stream>>>(
      s_bf, Wsb, bs, nullptr, x, nullptr, NTOK, DMODEL, KSTOCH, 2 * DMODEL, 0, 0, 4);
  gemm_kernel<false><<<128 * 4, 256, 0, stream>>>(
      d_bf, Wdb, bd, nullptr, x + DMODEL, nullptr, NTOK, DMODEL, KDETER, 2 * DMODEL, 0, 0, 4);

  // 3) q2 = emb[targets]
  gather_kernel<<<NTOK, 128, 0, stream>>>(emb, tg, q2);

  const int LN_GRID = (TWO_N + NTOK) / 4;
  for (int l = 0; l < 2; ++l) {
    // PreNorm (ln1) — both streams in one dispatch
    ln2_kernel<<<LN_GRID, 256, 0, stream>>>(x, q2, ln1g + 512 * l, ln1b + 512 * l, xnb, qnb);
    // qkv projection (no bias), bf16 out
    gemm_kernel<false><<<256 * 12, 256, 0, stream>>>(
        xnb, Wqkvb + (size_t)l * QKVD * DMODEL, nullptr, nullptr, nullptr, qkvb,
        TWO_N, QKVD, DMODEL, 0, QKVD, 0, 12);
    // attention (updates q2 in place with qout + qn)
    attn_kernel<<<NTOK * HEADS / 4, 256, 0, stream>>>(qkvb, qnb, q2, attnout);
    // out projection + bout + xn residual -> x
    gemm_kernel<false><<<256 * 4, 256, 0, stream>>>(
        attnout, Woutb + (size_t)l * DMODEL * DMODEL, bout + 512 * l, xnb, x, nullptr,
        TWO_N, DMODEL, DMODEL, DMODEL, 0, DMODEL, 4);
    // PreNorm (ln2) — both streams
    ln2_kernel<<<LN_GRID, 256, 0, stream>>>(x, q2, ln2g + 512 * l, ln2b + 512 * l, xnb, qnb);
    // FF x-stream
    gemm_kernel<true><<<256 * 8, 256, 0, stream>>>(
        xnb, W1bf + (size_t)l * FFDIM * DMODEL, b1 + 1024 * l, nullptr, nullptr, hb,
        TWO_N, FFDIM, DMODEL, 0, FFDIM, 0, 8);
    gemm_kernel<false><<<256 * 4, 256, 0, stream>>>(
        hb, W2bf + (size_t)l * DMODEL * FFDIM, b2 + 512 * l, xnb, x, nullptr,
        TWO_N, DMODEL, FFDIM, DMODEL, 0, DMODEL, 4);
    // FF q-stream (also keeps a bf16 copy of q2 for the head GEMM)
    gemm_kernel<true><<<128 * 8, 256, 0, stream>>>(
        qnb, W1bbf + (size_t)l * FFDIM * DMODEL, b1b + 1024 * l, nullptr, nullptr, hqb,
        NTOK, FFDIM, DMODEL, 0, FFDIM, 0, 8);
    gemm_kernel<false><<<128 * 4, 256, 0, stream>>>(
        hqb, W2bbf + (size_t)l * DMODEL * FFDIM, b2b + 512 * l, qnb, q2, q2b,
        NTOK, DMODEL, FFDIM, DMODEL, DMODEL, DMODEL, 4);
  }

  // head: mean = q2 @ Wm.T + bm  -> d_out [N,255] f32
  gemm_kernel<false><<<128 * 2, 256, 0, stream>>>(
      q2b, Wmb, bm, nullptr, out, nullptr, NTOK, NOUT, DMODEL, NOUT, 0, 0, 2);

  (void)in_sizes; (void)n_in; (void)out_size; (void)ws_size;
}

// Round 5
// 1793.816 us; speedup vs baseline: 1.1712x; 1.0088x over previous
//
#include <hip/hip_runtime.h>
#include <cstdint>
#include <cstddef>

// ---------------------------------------------------------------------------
// MixedHead: 2-layer dual-stream transformer forward on MI355X (gfx950).
// All GEMMs as bf16 MFMA (16x16x32), fp32 accumulate, fused epilogues.
// R5 == R4 resubmit (infra failure): x-stream bf16, fused f32->bf16 A-staging
// for tok GEMMs (no input cvt pass), LN reads bf16 x. q2 stream stays f32.
// ---------------------------------------------------------------------------

#define NTOK   16384      // B*T
#define TWO_N  32768
#define DMODEL 512
#define HEADS  8
#define HDIM   64
#define FFDIM  1024
#define KSTOCH 1024
#define KDETER 4096
#define QKVD   1536
#define NOUT   255

typedef short bf16x8 __attribute__((ext_vector_type(8)));
typedef float f32x4  __attribute__((ext_vector_type(4)));

__device__ inline unsigned short bfbits(float f) {
  union { float f; unsigned u; } x; x.f = f;
  unsigned r = x.u + 0x7fffu + ((x.u >> 16) & 1u);   // RNE
  return (unsigned short)(r >> 16);
}
__device__ inline float bf2f(unsigned short s) {
  union { unsigned u; float f; } x; x.u = ((unsigned)s) << 16;
  return x.f;
}
__device__ inline float wave_sum(float v) {
  #pragma unroll
  for (int o = 32; o > 0; o >>= 1) v += __shfl_xor(v, o);
  return v;
}

// ---------------------------------------------------------------------------
// Batched f32 -> bf16 conversion (weights only now). Wm padded to 256 rows.
// ---------------------------------------------------------------------------
struct CvtEnt { const float* src; unsigned short* dst; int n4; int ntot4; };
struct CvtArgs { CvtEnt e[9]; };

__global__ __launch_bounds__(256) void cvt_kernel(CvtArgs args) {
  CvtEnt ent = args.e[blockIdx.y];
  int stride = gridDim.x * 256;
  for (int i = blockIdx.x * 256 + threadIdx.x; i < ent.ntot4; i += stride) {
    float4 v;
    if (i < ent.n4) v = ((const float4*)ent.src)[i];
    else            v = make_float4(0.f, 0.f, 0.f, 0.f);
    ushort4 o;
    o.x = bfbits(v.x); o.y = bfbits(v.y); o.z = bfbits(v.z); o.w = bfbits(v.w);
    ((ushort4*)ent.dst)[i] = o;
  }
}

// q2[n,:] = emb[tg[n],:]   (f32 row gather, 1 block per row, float4 copies)
__global__ __launch_bounds__(128) void gather_kernel(
    const float* __restrict__ emb, const int* __restrict__ tg,
    float* __restrict__ q2) {
  int n = blockIdx.x;
  int row = tg[n];
  ((float4*)(q2 + (size_t)n * DMODEL))[threadIdx.x] =
      ((const float4*)(emb + (size_t)row * DMODEL))[threadIdx.x];
}

// ---------------------------------------------------------------------------
// LayerNorm over D=512 for BOTH streams in one dispatch. One wave per row.
// x stream is bf16 input; q stream is f32 input. Outputs bf16.
// rows [0, TWO_N) -> x stream; rows [TWO_N, TWO_N+NTOK) -> q stream.
// ---------------------------------------------------------------------------
__global__ __launch_bounds__(256) void ln2_kernel(
    const unsigned short* __restrict__ xs, const float* __restrict__ qs,
    const float* __restrict__ g, const float* __restrict__ b,
    unsigned short* __restrict__ xb, unsigned short* __restrict__ qb) {
  int w = threadIdx.x >> 6, l = threadIdx.x & 63;
  int row = blockIdx.x * 4 + w;
  float e[8];
  unsigned short* dst;
  if (row < TWO_N) {
    const unsigned short* src = xs + (size_t)row * DMODEL;
    bf16x8 v = ((const bf16x8*)src)[l];
    #pragma unroll
    for (int i = 0; i < 8; ++i) e[i] = bf2f((unsigned short)v[i]);
    dst = xb + (size_t)row * DMODEL;
  } else {
    int r2 = row - TWO_N;
    const float* src = qs + (size_t)r2 * DMODEL;
    float4 v0 = ((const float4*)src)[2 * l];
    float4 v1 = ((const float4*)src)[2 * l + 1];
    e[0] = v0.x; e[1] = v0.y; e[2] = v0.z; e[3] = v0.w;
    e[4] = v1.x; e[5] = v1.y; e[6] = v1.z; e[7] = v1.w;
    dst = qb + (size_t)r2 * DMODEL;
  }
  float s = 0.f, ss = 0.f;
  #pragma unroll
  for (int i = 0; i < 8; ++i) { s += e[i]; ss += e[i] * e[i]; }
  s = wave_sum(s); ss = wave_sum(ss);
  float mean = s * (1.f / DMODEL);
  float var  = ss * (1.f / DMODEL) - mean * mean;
  float r = rsqrtf(var + 1e-5f);

  // g,b: 8 consecutive f32 at l*8
  float4 g0 = ((const float4*)g)[2 * l], g1 = ((const float4*)g)[2 * l + 1];
  float4 b0 = ((const float4*)b)[2 * l], b1 = ((const float4*)b)[2 * l + 1];
  float gg[8] = {g0.x, g0.y, g0.z, g0.w, g1.x, g1.y, g1.z, g1.w};
  float bb[8] = {b0.x, b0.y, b0.z, b0.w, b1.x, b1.y, b1.z, b1.w};
  bf16x8 o;
  #pragma unroll
  for (int i = 0; i < 8; ++i)
    o[i] = (short)bfbits((e[i] - mean) * r * gg[i] + bb[i]);
  ((bf16x8*)dst)[l] = o;
}

// ---------------------------------------------------------------------------
// Attention: seq-len-2 log-softmax attention + cross-stream query.
// One wave per (token, head); lane = d in [0,64).
// ---------------------------------------------------------------------------
__global__ __launch_bounds__(256) void attn_kernel(
    const unsigned short* __restrict__ qkv, const unsigned short* __restrict__ qnb,
    float* __restrict__ q2, unsigned short* __restrict__ attnout) {
  int w = threadIdx.x >> 6, l = threadIdx.x & 63;
  int idx = blockIdx.x * 4 + w;          // n*HEADS + h
  int n = idx >> 3, h = idx & 7;
  const unsigned short* r0 = qkv + (size_t)(2 * n) * QKVD + h * HDIM + l;
  float q0 = bf2f(r0[0]),     k0 = bf2f(r0[512]),      v0 = bf2f(r0[1024]);
  float q1 = bf2f(r0[QKVD]),  k1 = bf2f(r0[QKVD+512]), v1 = bf2f(r0[QKVD+1024]);
  size_t qoff = (size_t)n * DMODEL + h * HDIM + l;
  float qq = bf2f(qnb[qoff]);

  float d00 = q0*k0, d01 = q0*k1, d10 = q1*k0, d11 = q1*k1, e0 = qq*k0, e1 = qq*k1;
  #pragma unroll
  for (int o = 32; o > 0; o >>= 1) {
    d00 += __shfl_xor(d00, o); d01 += __shfl_xor(d01, o);
    d10 += __shfl_xor(d10, o); d11 += __shfl_xor(d11, o);
    e0  += __shfl_xor(e0, o);  e1  += __shfl_xor(e1, o);
  }
  const float SC = 0.125f;   // 64^-0.5
  d00 *= SC; d01 *= SC; d10 *= SC; d11 *= SC; e0 *= SC; e1 *= SC;
  auto lsm2 = [](float& a, float& b) {
    float m = fmaxf(a, b);
    float lse = m + logf(expf(a - m) + expf(b - m));
    a -= lse; b -= lse;
  };
  lsm2(d00, d01); lsm2(d10, d11); lsm2(e0, e1);

  float o0 = d00 * v0 + d01 * v1;
  float o1 = d10 * v0 + d11 * v1;
  float oq = e0 * v0 + e1 * v1;
  attnout[(size_t)(2 * n)     * DMODEL + h * HDIM + l] = bfbits(o0);
  attnout[(size_t)(2 * n + 1) * DMODEL + h * HDIM + l] = bfbits(o1);
  q2[qoff] = oq + qq;
}

// ---------------------------------------------------------------------------
// bf16 MFMA GEMM: C[M,N] = A[M,K] * B[N,K]^T  (+bias, +GELU, +bf16 res)
// 128x128 tile, 4 waves (2x2), 4x4 16x16x32 frags each, BK=64.
// AF32=false: A bf16 via global_load_lds (m97 staging).
// AF32=true:  A f32 reg-staged (load float4 x2 -> cvt -> ds_write_b128);
//             fuses the input f32->bf16 conversion into the GEMM.
// T1 XCD-aware bijective block swizzle.
// ---------------------------------------------------------------------------
template <bool GELU, bool AF32>
__global__ __launch_bounds__(256, AF32 ? 2 : 3) void gemm_kernel(
    const void* __restrict__ Av, const unsigned short* __restrict__ B,
    const float* __restrict__ bias, const unsigned short* __restrict__ res,
    float* __restrict__ Cf, unsigned short* __restrict__ Cb,
    int M, int Nvalid, int K, int ldc, int ldcb, int ldres, int ntn) {
  __shared__ short lsA[128 * 64];
  __shared__ short lsB[128 * 64];
  // T1: bijective chunked XCD swizzle.
  int nwg = gridDim.x;
  int q8 = nwg >> 3, r8 = nwg & 7;
  int xcd = blockIdx.x & 7, lin = blockIdx.x >> 3;
  int bid = (xcd < r8 ? xcd * (q8 + 1) : r8 * (q8 + 1) + (xcd - r8) * q8) + lin;
  int tm = bid / ntn, tn = bid % ntn;
  int tid = threadIdx.x;
  int w = tid >> 6, l = tid & 63;
  int wr = w >> 1, wc = w & 1;

  int srow = w * 32 + (l >> 3);
  int scol = (l & 7) * 8;
  const unsigned short* ga = nullptr;
  const float* gaf = nullptr;
  if (AF32) gaf = (const float*)Av + (size_t)(tm * 128 + srow) * K + scol;
  else      ga  = (const unsigned short*)Av + (size_t)(tm * 128 + srow) * K + scol;
  const unsigned short* gb = B + (size_t)(tn * 128 + srow) * K + scol;
  short* la = lsA + w * 2048;   // wave-uniform base for global_load_lds
  short* lb = lsB + w * 2048;
  short* lwa = lsA + w * 2048 + (l >> 3) * 64 + (l & 7) * 8;  // per-lane ds_write addr

  f32x4 acc[4][4] = {};

  for (int k0 = 0; k0 < K; k0 += 64) {
    #pragma unroll
    for (int r = 0; r < 4; ++r) {
      if (AF32) {
        float4 u0 = *(const float4*)(gaf + k0 + (size_t)r * 8 * K);
        float4 u1 = *(const float4*)(gaf + k0 + (size_t)r * 8 * K + 4);
        bf16x8 pk;
        pk[0] = (short)bfbits(u0.x); pk[1] = (short)bfbits(u0.y);
        pk[2] = (short)bfbits(u0.z); pk[3] = (short)bfbits(u0.w);
        pk[4] = (short)bfbits(u1.x); pk[5] = (short)bfbits(u1.y);
        pk[6] = (short)bfbits(u1.z); pk[7] = (short)bfbits(u1.w);
        *(bf16x8*)(lwa + r * 512) = pk;
      } else {
        __builtin_amdgcn_global_load_lds(
            (const __attribute__((address_space(1))) void*)(ga + k0 + (size_t)r * 8 * K),
            (__attribute__((address_space(3))) void*)(la + r * 512), 16, 0, 0);
      }
      __builtin_amdgcn_global_load_lds(
          (const __attribute__((address_space(1))) void*)(gb + k0 + (size_t)r * 8 * K),
          (__attribute__((address_space(3))) void*)(lb + r * 512), 16, 0, 0);
    }
    __syncthreads();
    #pragma unroll
    for (int kk = 0; kk < 2; ++kk) {
      bf16x8 af[4], bfr[4];
      #pragma unroll
      for (int i = 0; i < 4; ++i)
        af[i] = *(const bf16x8*)(lsA + (wr * 64 + i * 16 + (l & 15)) * 64 +
                                 kk * 32 + (l >> 4) * 8);
      #pragma unroll
      for (int i = 0; i < 4; ++i)
        bfr[i] = *(const bf16x8*)(lsB + (wc * 64 + i * 16 + (l & 15)) * 64 +
                                  kk * 32 + (l >> 4) * 8);
      #pragma unroll
      for (int mi = 0; mi < 4; ++mi)
        #pragma unroll
        for (int ni = 0; ni < 4; ++ni)
          acc[mi][ni] = __builtin_amdgcn_mfma_f32_16x16x32_bf16(
              af[mi], bfr[ni], acc[mi][ni], 0, 0, 0);
    }
    __syncthreads();
  }

  // epilogue: C/D layout col = lane&15, row = (lane>>4)*4 + reg
  int lr = l >> 4, lc = l & 15;
  #pragma unroll
  for (int mi = 0; mi < 4; ++mi) {
    #pragma unroll
    for (int ni = 0; ni < 4; ++ni) {
      int gn = tn * 128 + wc * 64 + ni * 16 + lc;
      bool okn = gn < Nvalid;
      float bv = (bias != nullptr && okn) ? bias[gn] : 0.f;
      f32x4 a = acc[mi][ni];
      #pragma unroll
      for (int j = 0; j < 4; ++j) {
        int gm = tm * 128 + wr * 64 + mi * 16 + lr * 4 + j;
        float v = a[j] + bv;
        if (GELU) v = 0.5f * v * (1.f + erff(v * 0.70710678118654752f));
        if (okn) {
          if (res) v += bf2f(res[(size_t)gm * ldres + gn]);
          if (Cf) Cf[(size_t)gm * ldc + gn] = v;
          if (Cb) Cb[(size_t)gm * ldcb + gn] = bfbits(v);
        }
      }
    }
  }
}

// ---------------------------------------------------------------------------
extern "C" void kernel_launch(void* const* d_in, const int* in_sizes, int n_in,
                              void* d_out, int out_size, void* d_ws, size_t ws_size,
                              hipStream_t stream) {
  const float* stoch = (const float*)d_in[0];
  const float* deter = (const float*)d_in[1];
  const int*   tg    = (const int*)d_in[2];
  const float* emb   = (const float*)d_in[3];
  const float* Ws    = (const float*)d_in[4];
  const float* bs    = (const float*)d_in[5];
  const float* Wd    = (const float*)d_in[6];
  const float* bd    = (const float*)d_in[7];
  const float* ln1g  = (const float*)d_in[8];
  const float* ln1b  = (const float*)d_in[9];
  const float* Wqkv  = (const float*)d_in[10];
  const float* Wout  = (const float*)d_in[11];
  const float* bout  = (const float*)d_in[12];
  const float* ln2g  = (const float*)d_in[13];
  const float* ln2b  = (const float*)d_in[14];
  const float* W1    = (const float*)d_in[15];
  const float* b1    = (const float*)d_in[16];
  const float* W2    = (const float*)d_in[17];
  const float* b2    = (const float*)d_in[18];
  const float* W1b   = (const float*)d_in[19];
  const float* b1b   = (const float*)d_in[20];
  const float* W2b   = (const float*)d_in[21];
  const float* b2b   = (const float*)d_in[22];
  const float* Wm    = (const float*)d_in[23];
  const float* bm    = (const float*)d_in[24];
  float* out = (float*)d_out;

  char* p = (char*)d_ws;
  size_t off = 0;
  auto alloc = [&](size_t bytes) {
    void* r = p + off;
    off += (bytes + 255) & ~(size_t)255;
    return r;
  };
  unsigned short* x    = (unsigned short*)alloc((size_t)TWO_N * DMODEL * 2);  // bf16 stream
  float*          q2   = (float*)alloc((size_t)NTOK * DMODEL * 4);            // f32 stream
  unsigned short* xnb  = (unsigned short*)alloc((size_t)TWO_N * DMODEL * 2);
  unsigned short* qnb  = (unsigned short*)alloc((size_t)NTOK * DMODEL * 2);
  unsigned short* qkvb = (unsigned short*)alloc((size_t)TWO_N * QKVD * 2);
  unsigned short* attnout = (unsigned short*)alloc((size_t)TWO_N * DMODEL * 2);
  unsigned short* q2b  = (unsigned short*)alloc((size_t)NTOK * DMODEL * 2);
  unsigned short* Wsb   = (unsigned short*)alloc((size_t)DMODEL * KSTOCH * 2);
  unsigned short* Wdb   = (unsigned short*)alloc((size_t)DMODEL * KDETER * 2);
  unsigned short* Wqkvb = (unsigned short*)alloc((size_t)2 * QKVD * DMODEL * 2);
  unsigned short* Woutb = (unsigned short*)alloc((size_t)2 * DMODEL * DMODEL * 2);
  unsigned short* W1bf  = (unsigned short*)alloc((size_t)2 * FFDIM * DMODEL * 2);
  unsigned short* W2bf  = (unsigned short*)alloc((size_t)2 * DMODEL * FFDIM * 2);
  unsigned short* W1bbf = (unsigned short*)alloc((size_t)2 * FFDIM * DMODEL * 2);
  unsigned short* W2bbf = (unsigned short*)alloc((size_t)2 * DMODEL * FFDIM * 2);
  unsigned short* Wmb   = (unsigned short*)alloc((size_t)256 * DMODEL * 2);
  // hb/hqb alias qkvb (dead after attention consumes it)
  unsigned short* hb  = qkvb;
  unsigned short* hqb = qkvb + (size_t)TWO_N * FFDIM;

  // 1) convert weights to bf16
  CvtArgs ca;
  ca.e[0] = { Ws,   Wsb,   DMODEL * KSTOCH / 4, DMODEL * KSTOCH / 4 };
  ca.e[1] = { Wd,   Wdb,   DMODEL * KDETER / 4, DMODEL * KDETER / 4 };
  ca.e[2] = { Wqkv, Wqkvb, 2 * QKVD * DMODEL / 4, 2 * QKVD * DMODEL / 4 };
  ca.e[3] = { Wout, Woutb, 2 * DMODEL * DMODEL / 4, 2 * DMODEL * DMODEL / 4 };
  ca.e[4] = { W1,   W1bf,  2 * FFDIM * DMODEL / 4, 2 * FFDIM * DMODEL / 4 };
  ca.e[5] = { W2,   W2bf,  2 * DMODEL * FFDIM / 4, 2 * DMODEL * FFDIM / 4 };
  ca.e[6] = { W1b,  W1bbf, 2 * FFDIM * DMODEL / 4, 2 * FFDIM * DMODEL / 4 };
  ca.e[7] = { W2b,  W2bbf, 2 * DMODEL * FFDIM / 4, 2 * DMODEL * FFDIM / 4 };
  ca.e[8] = { Wm,   Wmb,   NOUT * DMODEL / 4,   256 * DMODEL / 4 };
  cvt_kernel<<<dim3(256, 9), 256, 0, stream>>>(ca);

  // 2) token projections (f32 A fused-convert) into interleaved bf16 x[N,2,D]
  gemm_kernel<false, true><<<128 * 4, 256, 0, stream>>>(
      stoch, Wsb, bs, nullptr, nullptr, x, NTOK, DMODEL, KSTOCH, 0, 2 * DMODEL, 0, 4);
  gemm_kernel<false, true><<<128 * 4, 256, 0, stream>>>(
      deter, Wdb, bd, nullptr, nullptr, x + DMODEL, NTOK, DMODEL, KDETER, 0, 2 * DMODEL, 0, 4);

  // 3) q2 = emb[targets]  (f32)
  gather_kernel<<<NTOK, 128, 0, stream>>>(emb, tg, q2);

  const int LN_GRID = (TWO_N + NTOK) / 4;
  for (int l = 0; l < 2; ++l) {
    // PreNorm (ln1) — x bf16 in, q2 f32 in, bf16 out
    ln2_kernel<<<LN_GRID, 256, 0, stream>>>(x, q2, ln1g + 512 * l, ln1b + 512 * l, xnb, qnb);
    // qkv projection (no bias), bf16 out
    gemm_kernel<false, false><<<256 * 12, 256, 0, stream>>>(
        xnb, Wqkvb + (size_t)l * QKVD * DMODEL, nullptr, nullptr, nullptr, qkvb,
        TWO_N, QKVD, DMODEL, 0, QKVD, 0, 12);
    // attention (q2 += handled inside: q2 = attn_out + qn)
    attn_kernel<<<NTOK * HEADS / 4, 256, 0, stream>>>(qkvb, qnb, q2, attnout);
    // out projection + bout + xn residual -> x (bf16)
    gemm_kernel<false, false><<<256 * 4, 256, 0, stream>>>(
        attnout, Woutb + (size_t)l * DMODEL * DMODEL, bout + 512 * l, xnb, nullptr, x,
        TWO_N, DMODEL, DMODEL, 0, DMODEL, DMODEL, 4);
    // PreNorm (ln2)
    ln2_kernel<<<LN_GRID, 256, 0, stream>>>(x, q2, ln2g + 512 * l, ln2b + 512 * l, xnb, qnb);
    // FF x-stream
    gemm_kernel<true, false><<<256 * 8, 256, 0, stream>>>(
        xnb, W1bf + (size_t)l * FFDIM * DMODEL, b1 + 1024 * l, nullptr, nullptr, hb,
        TWO_N, FFDIM, DMODEL, 0, FFDIM, 0, 8);
    gemm_kernel<false, false><<<256 * 4, 256, 0, stream>>>(
        hb, W2bf + (size_t)l * DMODEL * FFDIM, b2 + 512 * l, xnb, nullptr, x,
        TWO_N, DMODEL, FFDIM, 0, DMODEL, DMODEL, 4);
    // FF q-stream (writes q2 f32 and bf16 copy q2b for head)
    gemm_kernel<true, false><<<128 * 8, 256, 0, stream>>>(
        qnb, W1bbf + (size_t)l * FFDIM * DMODEL, b1b + 1024 * l, nullptr, nullptr, hqb,
        NTOK, FFDIM, DMODEL, 0, FFDIM, 0, 8);
    gemm_kernel<false, false><<<128 * 4, 256, 0, stream>>>(
        hqb, W2bbf + (size_t)l * DMODEL * FFDIM, b2b + 512 * l, qnb, q2, q2b,
        NTOK, DMODEL, FFDIM, DMODEL, DMODEL, DMODEL, 4);
  }

  // head: mean = q2 @ Wm.T + bm  -> d_out [N,255] f32
  gemm_kernel<false, false><<<128 * 2, 256, 0, stream>>>(
      q2b, Wmb, bm, nullptr, out, nullptr, NTOK, NOUT, DMODEL, NOUT, 0, 0, 2);

  (void)in_sizes; (void)n_in; (void)out_size; (void)ws_size;
}